// Round 1
// baseline (110.632 us; speedup 1.0000x reference)
//
#include <hip/hip_runtime.h>

#define EPS 1e-6

constexpr int B = 8, C = 256, T = 16000;
constexpr int T4 = T / 4;          // 4000, T divisible by 4
constexpr int BT = B * T;          // 128000

// ---------------- Kernel 1: per-(b,t) channel sums ----------------
// grid (ceil(T/256), B), block 256. Lane-consecutive t => coalesced loads.
__global__ __launch_bounds__(256)
void colsum_kernel(const float* __restrict__ x,
                   float* __restrict__ S, float* __restrict__ S2) {
    int b = blockIdx.y;
    int t = blockIdx.x * 256 + threadIdx.x;
    if (t >= T) return;
    const float* xp = x + (size_t)b * C * T + t;
    float s = 0.f, s2 = 0.f;
#pragma unroll 8
    for (int c = 0; c < C; ++c) {
        float v = xp[(size_t)c * T];
        s  += v;
        s2 += v * v;
    }
    S [b * T + t] = s;
    S2[b * T + t] = s2;
}

// ---------------- Kernel 2: per-b inclusive scan -> mean, istd ----------------
// One block per b, 1024 threads (16 waves). Double-precision running scan.
__global__ __launch_bounds__(1024)
void scan_kernel(const float* __restrict__ S, const float* __restrict__ S2,
                 float* __restrict__ meanp, float* __restrict__ istdp) {
    int b    = blockIdx.x;
    int tid  = threadIdx.x;
    int lane = tid & 63;
    int wid  = tid >> 6;              // 0..15

    __shared__ double wsum[16], wsum2[16];
    __shared__ double carry[2];
    if (tid == 0) { carry[0] = 0.0; carry[1] = 0.0; }
    __syncthreads();

    for (int base = 0; base < T; base += 1024) {
        int  t     = base + tid;
        bool valid = (t < T);
        double s  = valid ? (double)S [b * T + t] : 0.0;
        double s2 = valid ? (double)S2[b * T + t] : 0.0;

        // wave-64 inclusive scan
        for (int off = 1; off < 64; off <<= 1) {
            double u  = __shfl_up(s,  off);
            double u2 = __shfl_up(s2, off);
            if (lane >= off) { s += u; s2 += u2; }
        }
        if (lane == 63) { wsum[wid] = s; wsum2[wid] = s2; }
        __syncthreads();

        double pre = carry[0], pre2 = carry[1];
        for (int w = 0; w < wid; ++w) { pre += wsum[w]; pre2 += wsum2[w]; }
        double cs = pre + s, cs2 = pre2 + s2;

        if (valid) {
            double cnt  = (double)(t + 1) * (double)C;
            double mean = cs / cnt;
            double var  = cs2 / cnt - mean * mean;
            double istd = 1.0 / sqrt(var + EPS);
            meanp[b * T + t] = (float)mean;
            istdp[b * T + t] = (float)istd;
        }
        __syncthreads();
        if (tid == 0) {
            double tot = carry[0], tot2 = carry[1];
            for (int w = 0; w < 16; ++w) { tot += wsum[w]; tot2 += wsum2[w]; }
            carry[0] = tot; carry[1] = tot2;
        }
        __syncthreads();
    }
}

// ---------------- Kernel 3: normalize, float4 over t ----------------
// grid (ceil(T4/256), C, B), block 256. One float4 per thread.
__global__ __launch_bounds__(256)
void norm_kernel(const float4* __restrict__ x4,
                 const float*  __restrict__ weight,
                 const float*  __restrict__ bias,
                 const float*  __restrict__ meanp,
                 const float*  __restrict__ istdp,
                 float4* __restrict__ y4) {
    int t4 = blockIdx.x * 256 + threadIdx.x;
    if (t4 >= T4) return;
    int c = blockIdx.y;
    int b = blockIdx.z;

    size_t idx = ((size_t)b * C + c) * T4 + t4;
    float4 xv = x4[idx];
    const float4 mv = *(const float4*)(meanp + (size_t)b * T + (size_t)t4 * 4);
    const float4 iv = *(const float4*)(istdp + (size_t)b * T + (size_t)t4 * 4);
    float w  = weight[c];
    float bb = bias[c];

    float4 o;
    o.x = w * (xv.x - mv.x) * iv.x + bb;
    o.y = w * (xv.y - mv.y) * iv.y + bb;
    o.z = w * (xv.z - mv.z) * iv.z + bb;
    o.w = w * (xv.w - mv.w) * iv.w + bb;
    y4[idx] = o;
}

extern "C" void kernel_launch(void* const* d_in, const int* in_sizes, int n_in,
                              void* d_out, int out_size, void* d_ws, size_t ws_size,
                              hipStream_t stream) {
    const float* x      = (const float*)d_in[0];
    const float* weight = (const float*)d_in[1];
    const float* bias   = (const float*)d_in[2];
    float* y = (float*)d_out;

    float* S    = (float*)d_ws;          // BT floats
    float* S2   = S  + BT;               // BT floats
    float* mea  = S2 + BT;               // BT floats
    float* istd = mea + BT;              // BT floats  (total 2 MB)

    dim3 g1((T + 255) / 256, B);
    colsum_kernel<<<g1, 256, 0, stream>>>(x, S, S2);

    scan_kernel<<<B, 1024, 0, stream>>>(S, S2, mea, istd);

    dim3 g3((T4 + 255) / 256, C, B);
    norm_kernel<<<g3, 256, 0, stream>>>((const float4*)x, weight, bias,
                                        mea, istd, (float4*)y);
}

// Round 2
// 74.873 us; speedup vs baseline: 1.4776x; 1.4776x over previous
//
#include <hip/hip_runtime.h>

#define EPS 1e-6

constexpr int B = 8, C = 256, T = 16000;
constexpr int T4 = T / 4;          // 4000, T divisible by 4
constexpr int BT = B * T;          // 128000

// ---------------- Kernel 1: per-(b,t) channel sums ----------------
// grid (ceil(T/256), B), block 256. Lane-consecutive t => coalesced loads.
__global__ __launch_bounds__(256)
void colsum_kernel(const float* __restrict__ x,
                   float* __restrict__ S, float* __restrict__ S2) {
    int b = blockIdx.y;
    int t = blockIdx.x * 256 + threadIdx.x;
    if (t >= T) return;
    const float* xp = x + (size_t)b * C * T + t;
    float s = 0.f, s2 = 0.f;
#pragma unroll 8
    for (int c = 0; c < C; ++c) {
        float v = xp[(size_t)c * T];
        s  += v;
        s2 += v * v;
    }
    S [b * T + t] = s;
    S2[b * T + t] = s2;
}

// ---------------- Kernel 2: per-b inclusive scan -> mean, istd ----------------
// One block per b, 1024 threads. Single-pass: 16 elems/thread local scan
// (double), wave shfl-scan of thread totals, LDS pass over 16 wave totals.
__global__ __launch_bounds__(1024)
void scan_kernel(const float* __restrict__ S, const float* __restrict__ S2,
                 float* __restrict__ meanp, float* __restrict__ istdp) {
    constexpr int PT = 16;                 // elements per thread; 1000 active
    int b    = blockIdx.x;
    int tid  = threadIdx.x;
    int lane = tid & 63;
    int wid  = tid >> 6;                   // 0..15
    int t0   = tid * PT;
    bool active = (t0 < T);

    double v[PT], v2[PT];
    if (active) {
        const float4* Sp  = (const float4*)(S  + b * T + t0);
        const float4* S2p = (const float4*)(S2 + b * T + t0);
#pragma unroll
        for (int j = 0; j < PT / 4; ++j) {
            float4 a  = Sp[j];
            float4 a2 = S2p[j];
            v [4*j+0] = a.x;  v [4*j+1] = a.y;  v [4*j+2] = a.z;  v [4*j+3] = a.w;
            v2[4*j+0] = a2.x; v2[4*j+1] = a2.y; v2[4*j+2] = a2.z; v2[4*j+3] = a2.w;
        }
    } else {
#pragma unroll
        for (int j = 0; j < PT; ++j) { v[j] = 0.0; v2[j] = 0.0; }
    }

    // thread-local inclusive scan
#pragma unroll
    for (int j = 1; j < PT; ++j) { v[j] += v[j-1]; v2[j] += v2[j-1]; }
    double ts = v[PT-1], ts2 = v2[PT-1];

    // wave-64 inclusive scan of thread totals
    double s = ts, s2 = ts2;
    for (int off = 1; off < 64; off <<= 1) {
        double u  = __shfl_up(s,  off);
        double u2 = __shfl_up(s2, off);
        if (lane >= off) { s += u; s2 += u2; }
    }
    double waveExcl  = s  - ts;
    double waveExcl2 = s2 - ts2;

    __shared__ double wtot[16], wtot2[16];
    if (lane == 63) { wtot[wid] = s; wtot2[wid] = s2; }
    __syncthreads();

    double base = 0.0, base2 = 0.0;
    for (int w = 0; w < wid; ++w) { base += wtot[w]; base2 += wtot2[w]; }
    double off0  = base  + waveExcl;
    double off02 = base2 + waveExcl2;

    if (active) {
        float m[PT], is[PT];
#pragma unroll
        for (int j = 0; j < PT; ++j) {
            double cs   = off0  + v[j];
            double cs2  = off02 + v2[j];
            double cnt  = (double)(t0 + j + 1) * (double)C;
            double mean = cs / cnt;
            double var  = cs2 / cnt - mean * mean;
            double istd = 1.0 / sqrt(var + EPS);
            m [j] = (float)mean;
            is[j] = (float)istd;
        }
        float4* mp = (float4*)(meanp + b * T + t0);
        float4* ip = (float4*)(istdp + b * T + t0);
#pragma unroll
        for (int j = 0; j < PT / 4; ++j) {
            mp[j] = make_float4(m [4*j+0], m [4*j+1], m [4*j+2], m [4*j+3]);
            ip[j] = make_float4(is[4*j+0], is[4*j+1], is[4*j+2], is[4*j+3]);
        }
    }
}

// ---------------- Kernel 3: normalize, float4 over t ----------------
// grid (ceil(T4/256), C, B), block 256. One float4 per thread.
__global__ __launch_bounds__(256)
void norm_kernel(const float4* __restrict__ x4,
                 const float*  __restrict__ weight,
                 const float*  __restrict__ bias,
                 const float*  __restrict__ meanp,
                 const float*  __restrict__ istdp,
                 float4* __restrict__ y4) {
    int t4 = blockIdx.x * 256 + threadIdx.x;
    if (t4 >= T4) return;
    int c = blockIdx.y;
    int b = blockIdx.z;

    size_t idx = ((size_t)b * C + c) * T4 + t4;
    float4 xv = x4[idx];
    const float4 mv = *(const float4*)(meanp + (size_t)b * T + (size_t)t4 * 4);
    const float4 iv = *(const float4*)(istdp + (size_t)b * T + (size_t)t4 * 4);
    float w  = weight[c];
    float bb = bias[c];

    float4 o;
    o.x = w * (xv.x - mv.x) * iv.x + bb;
    o.y = w * (xv.y - mv.y) * iv.y + bb;
    o.z = w * (xv.z - mv.z) * iv.z + bb;
    o.w = w * (xv.w - mv.w) * iv.w + bb;
    y4[idx] = o;
}

extern "C" void kernel_launch(void* const* d_in, const int* in_sizes, int n_in,
                              void* d_out, int out_size, void* d_ws, size_t ws_size,
                              hipStream_t stream) {
    const float* x      = (const float*)d_in[0];
    const float* weight = (const float*)d_in[1];
    const float* bias   = (const float*)d_in[2];
    float* y = (float*)d_out;

    float* S    = (float*)d_ws;          // BT floats
    float* S2   = S  + BT;               // BT floats
    float* mea  = S2 + BT;               // BT floats
    float* istd = mea + BT;              // BT floats  (total 2 MB)

    dim3 g1((T + 255) / 256, B);
    colsum_kernel<<<g1, 256, 0, stream>>>(x, S, S2);

    scan_kernel<<<B, 1024, 0, stream>>>(S, S2, mea, istd);

    dim3 g3((T4 + 255) / 256, C, B);
    norm_kernel<<<g3, 256, 0, stream>>>((const float4*)x, weight, bias,
                                        mea, istd, (float4*)y);
}